// Round 8
// baseline (1475.323 us; speedup 1.0000x reference)
//
#include <hip/hip_runtime.h>
#include <hip/hip_bf16.h>
#include <cstdint>
#include <cstddef>

#define TK 8192
#define DIM 1024
#define HID 4096
#define NE 8

#define SK 32                 // K subtile
#define NSUB1 (DIM / SK)      // 32
#define NSUB2 (HID / SK)      // 128
#define ASZ 4096              // ushorts per A LDS buffer (128 rows x 32)

typedef __attribute__((ext_vector_type(8))) __bf16 bfrag;
typedef __attribute__((ext_vector_type(4))) float ffrag;

static __device__ __forceinline__ ushort f2bf(float f) {
    union { float f; uint32_t u; } v; v.f = f;
    uint32_t r = (v.u + 0x7fffu + ((v.u >> 16) & 1u)) >> 16;   // RNE, finite only
    return (ushort)r;
}

static __device__ __forceinline__ uint4 pack8(float4 a, float4 b) {
    union { ushort u[8]; uint4 q; } pk;
    pk.u[0] = f2bf(a.x); pk.u[1] = f2bf(a.y); pk.u[2] = f2bf(a.z); pk.u[3] = f2bf(a.w);
    pk.u[4] = f2bf(b.x); pk.u[5] = f2bf(b.y); pk.u[6] = f2bf(b.z); pk.u[7] = f2bf(b.w);
    return pk.q;
}

static __device__ __forceinline__ void gld16(const ushort* g, ushort* l) {
    __builtin_amdgcn_global_load_lds(
        (const __attribute__((address_space(1))) unsigned int*)g,
        (__attribute__((address_space(3))) unsigned int*)l, 16, 0, 0);
}

#define BARRIER() asm volatile("s_barrier" ::: "memory")
#define WAITVM(N) asm volatile("s_waitcnt vmcnt(" #N ")" ::: "memory")

// A LDS tile [128 rows][32 bf16], superblocks 8 rows x 4 chunks(16B):
// chunk (r,kc) at 16B-slot (r>>3)*32 + kc*8 + (r&7); 0 conflicts measured (r3-r7).
#define LDSIDX(r, kc) ((((r) >> 3) << 8) + ((kc) << 6) + (((r) & 7) << 3))
#define SLOT_R(s)  ((((s) >> 5) << 3) | ((s) & 7))
#define SLOT_KC(s) (((s) >> 3) & 3)

// ---------------- f32 -> bf16 plain convert (x) ----------------
__global__ __launch_bounds__(256) void k_cvt(const float* __restrict__ src,
                                             ushort* __restrict__ dst, int n8) {
    int i = blockIdx.x * blockDim.x + threadIdx.x;
    if (i >= n8) return;
    const float4* p = (const float4*)src + (size_t)i * 2;
    ((uint4*)dst)[i] = pack8(p[0], p[1]);
}

// ---------------- w1/w3 -> interleaved fragment-tiled bf16 ----------------
// group g = e*512 + nt*8 + gg  (nt 0..63 panels of 64 h-cols; gg 0..7, even=w1 odd=w3)
// tile: [g][kb 0..31][chunk 0..63], chunk c: row15=c&15, kc=c>>4 -> 16B of
// (h = nt*64 + ((gg>>1)<<4)|row15, k = kb*32 + kc*8..+8)
__global__ __launch_bounds__(256) void k_cvt_w13t(const float* __restrict__ w1,
                                                  const float* __restrict__ w3,
                                                  ushort* __restrict__ dst) {
    int i = blockIdx.x * blockDim.x + threadIdx.x;   // 8,388,608 chunks
    int cc = i & 63, kb = (i >> 6) & 31, g = i >> 11;
    int e = g >> 9, nt = (g >> 3) & 63, gg = g & 7;
    int row15 = cc & 15, kc = cc >> 4;
    int h = nt * 64 + (((gg >> 1) << 4) | row15);
    const float* src = (gg & 1) ? w3 : w1;
    const float* p = src + ((size_t)e * HID + h) * DIM + kb * 32 + kc * 8;
    ((uint4*)dst)[i] = pack8(*(const float4*)p, *(const float4*)(p + 4));
}

// ---------------- w2 -> fragment-tiled bf16 ----------------
// group g = e*64 + nt*8 + g2 (nt 0..7 panels of 128 out-cols); [g][kb 0..127][c 0..63]
__global__ __launch_bounds__(256) void k_cvt_w2t(const float* __restrict__ w2,
                                                 ushort* __restrict__ dst) {
    int i = blockIdx.x * blockDim.x + threadIdx.x;   // 4,194,304 chunks
    int cc = i & 63, kb = (i >> 6) & 127, g = i >> 13;
    int e = g >> 6, nt = (g >> 3) & 7, g2 = g & 7;
    int row15 = cc & 15, kc = cc >> 4;
    int row = nt * 128 + g2 * 16 + row15;            // out col
    const float* p = w2 + ((size_t)e * DIM + row) * HID + kb * 32 + kc * 8;
    ((uint4*)dst)[i] = pack8(*(const float4*)p, *(const float4*)(p + 4));
}

// ---------------- router: f64-accurate logits, top-2, renormalized ----------------
__global__ __launch_bounds__(256) void k_router(const float* __restrict__ x,
                                                const float* __restrict__ gw,
                                                int* __restrict__ topi, float* __restrict__ topw) {
    int t = blockIdx.x * 4 + (threadIdx.x >> 6);
    int lane = threadIdx.x & 63;
    if (t >= TK) return;
    double acc[NE];
#pragma unroll
    for (int e = 0; e < NE; ++e) acc[e] = 0.0;
    const float* xr = x + (size_t)t * DIM;
    for (int k = lane; k < DIM; k += 64) {
        double xv = (double)xr[k];
#pragma unroll
        for (int e = 0; e < NE; ++e) acc[e] += xv * (double)gw[e * DIM + k];
    }
#pragma unroll
    for (int e = 0; e < NE; ++e) {
#pragma unroll
        for (int off = 32; off > 0; off >>= 1) acc[e] += __shfl_xor(acc[e], off);
    }
    if (lane == 0) {
        int i1 = 0;
#pragma unroll
        for (int e = 1; e < NE; ++e) if (acc[e] > acc[i1]) i1 = e;
        int i2 = (i1 == 0) ? 1 : 0;
#pragma unroll
        for (int e = 0; e < NE; ++e) if (e != i1 && acc[e] > acc[i2]) i2 = e;
        double w = 1.0 / (1.0 + exp(acc[i2] - acc[i1]));
        topi[t * 2 + 0] = i1; topi[t * 2 + 1] = i2;
        topw[t * 2 + 0] = (float)w; topw[t * 2 + 1] = (float)(1.0 - w);
    }
}

__global__ void k_count(const int* __restrict__ topi, int* __restrict__ counts) {
    int i = blockIdx.x * blockDim.x + threadIdx.x;
    if (i < 2 * TK) atomicAdd(&counts[topi[i]], 1);
}

__global__ void k_scan(const int* __restrict__ counts, int* __restrict__ offs,
                       int* __restrict__ cursor, int* __restrict__ desc,
                       int* __restrict__ ndesc) {
    if (threadIdx.x == 0 && blockIdx.x == 0) {
        int s = 0, d = 0;
        for (int e = 0; e < NE; ++e) {
            offs[e] = s; cursor[e] = s;
            int tiles = (counts[e] + 127) >> 7;
            for (int t = 0; t < tiles; ++t) desc[d++] = (e << 16) | t;
            s += counts[e];
        }
        offs[NE] = s;
        ndesc[0] = d;
    }
}

__global__ void k_scatter(const int* __restrict__ topi, const float* __restrict__ topw,
                          int* __restrict__ cursor, int* __restrict__ perm, float* __restrict__ pw) {
    int t = blockIdx.x * blockDim.x + threadIdx.x;
    if (t >= TK) return;
#pragma unroll
    for (int k = 0; k < 2; ++k) {
        int e = topi[t * 2 + k];
        int pos = atomicAdd(&cursor[e], 1);
        perm[pos] = t; pw[pos] = topw[t * 2 + k];
    }
}

// ================= GEMM cores: A via LDS ring, B direct-from-global frags =================
// 256 threads = 4 waves (2M x 2N), per-wave 64x64 (acc 64 regs). Per subtile per wave:
// 2 gld16 (A) + 4 reg B-loads + 4 ds_read + 16 MFMA. One barrier + one counted vmcnt.
// Ledger (order per iter: ...MFMA(X); LOADB(X+1); STGA(X+2)): outstanding at WAIT(X) =
// A(X)x2, B(X)x4, A(X+1)x2 -> vmcnt(2) retires A(X),B(X), keeps A(X+1). Last iter vmcnt(0).
// NBUF=4, unroll 4 for static LDS buf + reg indices.

// ---------------- GEMM A (fused): H = silu(x@w1^T) * (x@w3^T) ----------------
__global__ __launch_bounds__(256, 4) void k_ffn1(const ushort* __restrict__ xb,
                                                 const ushort* __restrict__ w13t,
                                                 const int* __restrict__ offs,
                                                 const int* __restrict__ perm,
                                                 const int* __restrict__ desc,
                                                 const int* __restrict__ ndesc_g,
                                                 ushort* __restrict__ H) {
    __shared__ ushort lA[4 * ASZ];
    __shared__ int lTok[128];

    const int tid = threadIdx.x;
    const int lane = tid & 63, wid = tid >> 6;
    const int l15 = lane & 15, kcc = lane >> 4;
    const int wm = (wid >> 1) * 64;
    const int wn = (wid & 1) * 64;
    const int gbase = wn >> 4;                     // 0 or 4

    const int rA0 = SLOT_R(tid), kA0 = SLOT_KC(tid);
    const int rA1 = SLOT_R(tid + 256), kA1 = SLOT_KC(tid + 256);

    const int nitems = ndesc_g[0] << 6;            // 64 nt-panels per desc

    bfrag a[4], br[4];
    ffrag acc[4][4];

#pragma unroll 1
    for (int w = blockIdx.x; w < nitems; w += (int)gridDim.x) {
        __syncthreads();                           // prev item fully done with lA
        const int de = desc[w >> 6];
        const int e = de >> 16, mt = de & 0xffff, nt = w & 63;
        const int m0 = offs[e] + (mt << 7);
        const int nrows = min(128, offs[e + 1] - m0);
        if (tid < 128) lTok[tid] = (tid < nrows) ? perm[m0 + tid] : perm[m0];
        __syncthreads();

        const ushort* pA0 = xb + (size_t)lTok[rA0] * DIM + kA0 * 8;
        const ushort* pA1 = xb + (size_t)lTok[rA1] * DIM + kA1 * 8;
        const ushort* pBw = w13t + ((size_t)(e * 512 + nt * 8 + gbase) << 14) + lane * 8;

#pragma unroll
        for (int i = 0; i < 4; ++i)
#pragma unroll
            for (int j = 0; j < 4; ++j) acc[i][j] = (ffrag)0.f;

#define STGA1(buf, sx) do { \
            gld16(pA0 + (sx) * SK, lA + (buf) * ASZ + wid * 512); \
            gld16(pA1 + (sx) * SK, lA + (buf) * ASZ + 2048 + wid * 512); } while (0)
#define LOADB1(kb) { _Pragma("unroll") \
            for (int j = 0; j < 4; ++j) \
                br[j] = *(const bfrag*)(pBw + ((size_t)j << 14) + (size_t)(kb) * 512); }
#define ITER1(X, BR, BW) do { \
            if ((X) == NSUB1 - 1) { WAITVM(0); } else { WAITVM(2); } \
            BARRIER(); \
            _Pragma("unroll") \
            for (int i = 0; i < 4; ++i) \
                a[i] = *(const bfrag*)&lA[(BR) * ASZ + LDSIDX(wm + i * 16 + l15, kcc)]; \
            __builtin_amdgcn_s_setprio(1); \
            _Pragma("unroll") \
            for (int i = 0; i < 4; ++i) \
                _Pragma("unroll") \
                for (int j = 0; j < 4; ++j) \
                    acc[i][j] = __builtin_amdgcn_mfma_f32_16x16x32_bf16(a[i], br[j], acc[i][j], 0, 0, 0); \
            __builtin_amdgcn_s_setprio(0); \
            if ((X) + 1 < NSUB1) LOADB1((X) + 1); \
            if ((X) + 2 < NSUB1) STGA1(BW, (X) + 2); \
        } while (0)

        STGA1(0, 0);
        LOADB1(0);
        STGA1(1, 1);
#pragma unroll 1
        for (int X4 = 0; X4 < NSUB1; X4 += 4) {
            ITER1(X4 + 0, 0, 2);
            ITER1(X4 + 1, 1, 3);
            ITER1(X4 + 2, 2, 0);
            ITER1(X4 + 3, 3, 1);
        }
#undef ITER1
#undef LOADB1
#undef STGA1

        // epilogue: frag pairs (jf, jf+1) = (h1, h3) for same 16 hidden cols
#pragma unroll
        for (int i = 0; i < 4; ++i) {
            int rbase = wm + i * 16 + ((lane >> 4) << 2);
#pragma unroll
            for (int q = 0; q < 4; ++q) {
                int rl = rbase + q;
                if (rl >= nrows) continue;
                size_t rowoff = (size_t)(m0 + rl) * HID;
#pragma unroll
                for (int jf = 0; jf < 4; jf += 2) {
                    int gg = gbase + jf;
                    int col = nt * 64 + ((gg >> 1) << 4) + l15;
                    float h1 = acc[i][jf][q], h3 = acc[i][jf + 1][q];
                    H[rowoff + col] = f2bf((h1 / (1.f + __expf(-h1))) * h3);
                }
            }
        }
    }
}

// ---------------- GEMM B: out[tok,:] += pw[pos] * (H[pos,:] @ w2^T) ----------------
__global__ __launch_bounds__(256, 4) void k_ffn2(const ushort* __restrict__ H,
                                                 const ushort* __restrict__ w2t,
                                                 const int* __restrict__ offs,
                                                 const int* __restrict__ perm,
                                                 const float* __restrict__ pw,
                                                 const int* __restrict__ desc,
                                                 const int* __restrict__ ndesc_g,
                                                 float* __restrict__ out) {
    __shared__ ushort lA[4 * ASZ];
    __shared__ int lTok[128];
    __shared__ float lPw[128];

    const int tid = threadIdx.x;
    const int lane = tid & 63, wid = tid >> 6;
    const int l15 = lane & 15, kcc = lane >> 4;
    const int wm = (wid >> 1) * 64;
    const int wn = (wid & 1) * 64;
    const int gbase = wn >> 4;

    const int rA0 = SLOT_R(tid), kA0 = SLOT_KC(tid);
    const int rA1 = SLOT_R(tid + 256), kA1 = SLOT_KC(tid + 256);

    const int nitems = ndesc_g[0] << 3;            // 8 nt-panels of 128 cols

    bfrag a[4], br[4];
    ffrag acc[4][4];

#pragma unroll 1
    for (int w = blockIdx.x; w < nitems; w += (int)gridDim.x) {
        __syncthreads();
        const int de = desc[w >> 3];
        const int e = de >> 16, mt = de & 0xffff, nt = w & 7;
        const int m0 = offs[e] + (mt << 7);
        const int nrows = min(128, offs[e + 1] - m0);
        if (tid < 128) {
            bool v = tid < nrows;
            lTok[tid] = v ? perm[m0 + tid] : 0;
            lPw[tid]  = v ? pw[m0 + tid] : 0.f;
        }
        __syncthreads();

        int p0 = m0 + rA0; if (p0 > 2 * TK - 1) p0 = 2 * TK - 1;
        int p1 = m0 + rA1; if (p1 > 2 * TK - 1) p1 = 2 * TK - 1;
        const ushort* pA0 = H + (size_t)p0 * HID + kA0 * 8;
        const ushort* pA1 = H + (size_t)p1 * HID + kA1 * 8;
        const ushort* pBw = w2t + ((size_t)(e * 64 + nt * 8 + gbase) << 16) + lane * 8;

#pragma unroll
        for (int i = 0; i < 4; ++i)
#pragma unroll
            for (int j = 0; j < 4; ++j) acc[i][j] = (ffrag)0.f;

#define STGA2(buf, sx) do { \
            gld16(pA0 + (sx) * SK, lA + (buf) * ASZ + wid * 512); \
            gld16(pA1 + (sx) * SK, lA + (buf) * ASZ + 2048 + wid * 512); } while (0)
#define LOADB2(kb) { _Pragma("unroll") \
            for (int j = 0; j < 4; ++j) \
                br[j] = *(const bfrag*)(pBw + ((size_t)j << 16) + (size_t)(kb) * 512); }
#define ITER2(X, BR, BW) do { \
            if ((X) == NSUB2 - 1) { WAITVM(0); } else { WAITVM(2); } \
            BARRIER(); \
            _Pragma("unroll") \
            for (int i = 0; i < 4; ++i) \
                a[i] = *(const bfrag*)&lA[(BR) * ASZ + LDSIDX(wm + i * 16 + l15, kcc)]; \
            __builtin_amdgcn_s_setprio(1); \
            _Pragma("unroll") \
            for (int i = 0; i < 4; ++i) \
                _Pragma("unroll") \
                for (int j = 0; j < 4; ++j) \
                    acc[i][j] = __builtin_amdgcn_mfma_f32_16x16x32_bf16(a[i], br[j], acc[i][j], 0, 0, 0); \
            __builtin_amdgcn_s_setprio(0); \
            if ((X) + 1 < NSUB2) LOADB2((X) + 1); \
            if ((X) + 2 < NSUB2) STGA2(BW, (X) + 2); \
        } while (0)

        STGA2(0, 0);
        LOADB2(0);
        STGA2(1, 1);
#pragma unroll 1
        for (int X4 = 0; X4 < NSUB2; X4 += 4) {
            ITER2(X4 + 0, 0, 2);
            ITER2(X4 + 1, 1, 3);
            ITER2(X4 + 2, 2, 0);
            ITER2(X4 + 3, 3, 1);
        }
#undef ITER2
#undef LOADB2
#undef STGA2

#pragma unroll
        for (int i = 0; i < 4; ++i) {
            int rbase = wm + i * 16 + ((lane >> 4) << 2);
#pragma unroll
            for (int q = 0; q < 4; ++q) {
                int rl = rbase + q;
                if (rl >= nrows) continue;
                int tok = lTok[rl];
                float wgt = lPw[rl];
                size_t rowoff = (size_t)tok * DIM;
#pragma unroll
                for (int j = 0; j < 4; ++j) {
                    int col = nt * 128 + wn + j * 16 + l15;
                    atomicAdd(&out[rowoff + col], acc[i][j][q] * wgt);   // 2 adds/elem, deterministic
                }
            }
        }
    }
}

extern "C" void kernel_launch(void* const* d_in, const int* in_sizes, int n_in,
                              void* d_out, int out_size, void* d_ws, size_t ws_size,
                              hipStream_t stream) {
    const float* x  = (const float*)d_in[0];
    const float* gw = (const float*)d_in[1];
    const float* w1 = (const float*)d_in[2];
    const float* w2 = (const float*)d_in[3];   // dict order: x, gate_w, w1, w2, w3 !
    const float* w3 = (const float*)d_in[4];
    float* out = (float*)d_out;

    char* ws = (char*)d_ws;
    int*    topi   = (int*)(ws + 0);
    float*  topw   = (float*)(ws + 65536);
    int*    perm   = (int*)(ws + 131072);
    float*  pw     = (float*)(ws + 196608);
    int*    counts = (int*)(ws + 262144);
    int*    offs   = (int*)(ws + 262144 + 256);
    int*    cursor = (int*)(ws + 262144 + 512);
    int*    ndesc  = (int*)(ws + 262144 + 768);
    int*    desc   = (int*)(ws + 262144 + 1024);

    const size_t OFF_XB = 524288;                       // xb  : 16 MiB
    const size_t OFF_H  = OFF_XB + 16777216;            // H   : 128 MiB
    const size_t OFF_WT = OFF_H + 134217728;            // w13t: 128 MiB (w2t reuses, 64 MiB)

    ushort* xb   = (ushort*)(ws + OFF_XB);
    ushort* H    = (ushort*)(ws + OFF_H);
    ushort* w13t = (ushort*)(ws + OFF_WT);
    ushort* w2t  = (ushort*)(ws + OFF_WT);              // after ffn1, w13t is dead

    hipMemsetAsync(counts, 0, 32, stream);
    hipMemsetAsync(out, 0, (size_t)out_size * sizeof(float), stream);

    k_router<<<dim3(TK / 4), 256, 0, stream>>>(x, gw, topi, topw);
    k_count<<<dim3((2 * TK) / 256), 256, 0, stream>>>(topi, counts);
    k_scan<<<dim3(1), 64, 0, stream>>>(counts, offs, cursor, desc, ndesc);
    k_scatter<<<dim3(TK / 256), 256, 0, stream>>>(topi, topw, cursor, perm, pw);

    k_cvt<<<dim3((TK * DIM / 8) / 256), 256, 0, stream>>>(x, xb, TK * DIM / 8);
    k_cvt_w13t<<<dim3(32768), 256, 0, stream>>>(w1, w3, w13t);

    k_ffn1<<<dim3(1024), 256, 0, stream>>>(xb, w13t, offs, perm, desc, ndesc, H);

    k_cvt_w2t<<<dim3(16384), 256, 0, stream>>>(w2, w2t);

    k_ffn2<<<dim3(1024), 256, 0, stream>>>(H, w2t, offs, perm, pw, desc, ndesc, out);
}

// Round 9
// 1438.063 us; speedup vs baseline: 1.0259x; 1.0259x over previous
//
#include <hip/hip_runtime.h>
#include <hip/hip_bf16.h>
#include <cstdint>
#include <cstddef>

#define TK 8192
#define DIM 1024
#define HID 4096
#define NE 8

#define SK 32                  // K subtile
#define NSUB1 (DIM / SK)       // 32
#define NSUB2 (HID / SK)       // 128
#define NBUF 5                 // subtile ring: 4 in flight + 1 being read
#define ASZ 4096               // ushorts per A buffer (128 rows x 32)
#define BSZ 8192               // ushorts per B buffer (256 rows x 32)

typedef __attribute__((ext_vector_type(8))) __bf16 bfrag;
typedef __attribute__((ext_vector_type(4))) float ffrag;

static __device__ __forceinline__ ushort f2bf(float f) {
    union { float f; uint32_t u; } v; v.f = f;
    uint32_t r = (v.u + 0x7fffu + ((v.u >> 16) & 1u)) >> 16;   // RNE, finite only
    return (ushort)r;
}

static __device__ __forceinline__ uint4 pack8(float4 a, float4 b) {
    union { ushort u[8]; uint4 q; } pk;
    pk.u[0] = f2bf(a.x); pk.u[1] = f2bf(a.y); pk.u[2] = f2bf(a.z); pk.u[3] = f2bf(a.w);
    pk.u[4] = f2bf(b.x); pk.u[5] = f2bf(b.y); pk.u[6] = f2bf(b.z); pk.u[7] = f2bf(b.w);
    return pk.q;
}

static __device__ __forceinline__ void gld16(const ushort* g, ushort* l) {
    __builtin_amdgcn_global_load_lds(
        (const __attribute__((address_space(1))) unsigned int*)g,
        (__attribute__((address_space(3))) unsigned int*)l, 16, 0, 0);
}

#define BARRIER() asm volatile("s_barrier" ::: "memory")
#define WAITVM(N) asm volatile("s_waitcnt vmcnt(" #N ")" ::: "memory")

// LDS subtile [R rows][32 bf16], superblocks of 8 rows x 4 chunks(16B):
// chunk (r,kc) at 16B-slot (r>>3)*32 + kc*8 + (r&7); 0 bank conflicts measured (r3-r7).
// gld16 linear slot s: r = (s>>5)*8 + (s&7), kc = (s>>3)&3.
#define LDSIDX(r, kc) ((((r) >> 3) << 8) + ((kc) << 6) + (((r) & 7) << 3))
#define SLOT_R(s)  ((((s) >> 5) << 3) | ((s) & 7))
#define SLOT_KC(s) (((s) >> 3) & 3)

// ---------------- f32 -> bf16 streaming convert ----------------
__global__ __launch_bounds__(256) void k_cvt(const float* __restrict__ src,
                                             ushort* __restrict__ dst, int n8) {
    int i = blockIdx.x * blockDim.x + threadIdx.x;
    if (i >= n8) return;
    const float4* p = (const float4*)src + (size_t)i * 2;
    ((uint4*)dst)[i] = pack8(p[0], p[1]);
}

// ---------------- router: f64-accurate logits, top-2, renormalized ----------------
__global__ __launch_bounds__(256) void k_router(const float* __restrict__ x,
                                                const float* __restrict__ gw,
                                                int* __restrict__ topi, float* __restrict__ topw) {
    int t = blockIdx.x * 4 + (threadIdx.x >> 6);
    int lane = threadIdx.x & 63;
    if (t >= TK) return;
    double acc[NE];
#pragma unroll
    for (int e = 0; e < NE; ++e) acc[e] = 0.0;
    const float* xr = x + (size_t)t * DIM;
    for (int k = lane; k < DIM; k += 64) {
        double xv = (double)xr[k];
#pragma unroll
        for (int e = 0; e < NE; ++e) acc[e] += xv * (double)gw[e * DIM + k];
    }
#pragma unroll
    for (int e = 0; e < NE; ++e) {
#pragma unroll
        for (int off = 32; off > 0; off >>= 1) acc[e] += __shfl_xor(acc[e], off);
    }
    if (lane == 0) {
        int i1 = 0;
#pragma unroll
        for (int e = 1; e < NE; ++e) if (acc[e] > acc[i1]) i1 = e;
        int i2 = (i1 == 0) ? 1 : 0;
#pragma unroll
        for (int e = 0; e < NE; ++e) if (e != i1 && acc[e] > acc[i2]) i2 = e;
        double w = 1.0 / (1.0 + exp(acc[i2] - acc[i1]));
        topi[t * 2 + 0] = i1; topi[t * 2 + 1] = i2;
        topw[t * 2 + 0] = (float)w; topw[t * 2 + 1] = (float)(1.0 - w);
    }
}

__global__ void k_count(const int* __restrict__ topi, int* __restrict__ counts) {
    int i = blockIdx.x * blockDim.x + threadIdx.x;
    if (i < 2 * TK) atomicAdd(&counts[topi[i]], 1);
}

// builds per-expert offsets AND the M=128 tile descriptor list
__global__ void k_scan(const int* __restrict__ counts, int* __restrict__ offs,
                       int* __restrict__ cursor, int* __restrict__ desc,
                       int* __restrict__ ndesc) {
    if (threadIdx.x == 0 && blockIdx.x == 0) {
        int s = 0, d = 0;
        for (int e = 0; e < NE; ++e) {
            offs[e] = s; cursor[e] = s;
            int tiles = (counts[e] + 127) >> 7;
            for (int t = 0; t < tiles; ++t) desc[d++] = (e << 16) | t;
            s += counts[e];
        }
        offs[NE] = s;
        ndesc[0] = d;
    }
}

__global__ void k_scatter(const int* __restrict__ topi, const float* __restrict__ topw,
                          int* __restrict__ cursor, int* __restrict__ perm, float* __restrict__ pw) {
    int t = blockIdx.x * blockDim.x + threadIdx.x;
    if (t >= TK) return;
#pragma unroll
    for (int k = 0; k < 2; ++k) {
        int e = topi[t * 2 + k];
        int pos = atomicAdd(&cursor[e], 1);
        perm[pos] = t; pw[pos] = topw[t * 2 + k];
    }
}

// ================= persistent GEMM cores, 4-deep pipeline =================
// Tile 128(M) x 256(B-rows), 8 waves (2M x 4N), per-wave 64x64 (acc 64 regs).
// NBUF=5, stage X+4 during iter X (3 gld16/thread/subtile).
// Ledger: prologue stages 0..3 (12 loads). Iter X entry: WAITVM(9) retires
// subtile X's 3 loads (X+1..X+3 stay in flight); after barrier stage X+4 -> 12.
// Deadline for a load: 4 iters (~800 cyc) >= L2/HBM latency. Tail: staging stops
// at NSUB-1, outstanding drops 9/6/3 -> explicit WAITVM(6)/(3)/(0) iters.
// Single barrier/iter: reads of buf[X-1] complete before each wave's MFMA(X-1),
// which precedes barrier(X), so staging buf[(X+4)%5]=buf[(X-1)%5] after it is safe.

// ---------------- GEMM A (fused): H = silu(x@w1^T) * (x@w3^T) ----------------
// B rows interleave w1/w3 in 16-row groups -> (h1,h3) pairs wave-local; item
// covers 128 tokens x 128 hidden cols. items = ndesc * 32.
__global__ __launch_bounds__(512, 2) void k_ffn1(const ushort* __restrict__ xb,
                                                 const ushort* __restrict__ w1b,
                                                 const ushort* __restrict__ w3b,
                                                 const int* __restrict__ offs,
                                                 const int* __restrict__ perm,
                                                 const int* __restrict__ desc,
                                                 const int* __restrict__ ndesc_g,
                                                 ushort* __restrict__ H) {
    __shared__ ushort lA[NBUF * ASZ];   // 40 KiB
    __shared__ ushort lB[NBUF * BSZ];   // 80 KiB
    __shared__ int lTok[128];

    const int tid = threadIdx.x;
    const int lane = tid & 63, wid = tid >> 6;
    const int l15 = lane & 15, kcc = lane >> 4;
    const int wm = (wid >> 2) * 64;
    const int wn = (wid & 3) * 64;

    const int nitems = ndesc_g[0] << 5;

    const int rA = SLOT_R(tid), kcA = SLOT_KC(tid);

    bfrag a[4], b[4];
    ffrag acc[4][4];

#pragma unroll 1
    for (int w = blockIdx.x; w < nitems; w += (int)gridDim.x) {
        __syncthreads();   // prev item's readers/epilogue done before LDS reuse
        const int de = desc[w >> 5];
        const int e = de >> 16, mt = de & 0xffff, nt = w & 31;
        const int m0 = offs[e] + (mt << 7);
        const int nrows = min(128, offs[e + 1] - m0);
        if (tid < 128) lTok[tid] = (tid < nrows) ? perm[m0 + tid] : perm[m0];  // pad -> valid row, discarded
        __syncthreads();

        const ushort* pA = xb + (size_t)lTok[rA] * DIM + kcA * 8;
        const ushort* pBp[2];
        {
            const size_t ebase = (size_t)e * HID * DIM;
#pragma unroll
            for (int i2 = 0; i2 < 2; ++i2) {
                int s = i2 * 512 + tid;
                int r = SLOT_R(s), kc = SLOT_KC(s);
                int gg = r >> 4;
                int h = ((gg >> 1) << 4) | (r & 15);
                const ushort* wsrc = (gg & 1) ? w3b : w1b;
                pBp[i2] = wsrc + ebase + (size_t)(nt * 128 + h) * DIM + kc * 8;
            }
        }

#pragma unroll
        for (int i = 0; i < 4; ++i)
#pragma unroll
            for (int j = 0; j < 4; ++j) acc[i][j] = (ffrag)0.f;

#define STG1(buf, sx) do { if ((sx) < NSUB1) {                                   \
            gld16(pA + (sx) * SK, lA + (buf) * ASZ + (wid * 64) * 8);            \
            gld16(pBp[0] + (sx) * SK, lB + (buf) * BSZ + (wid * 64) * 8);        \
            gld16(pBp[1] + (sx) * SK, lB + (buf) * BSZ + (512 + wid * 64) * 8); } } while (0)

#define COMP1(bcur) do {                                                         \
            const ushort* A_ = lA + (bcur) * ASZ;                                \
            const ushort* B_ = lB + (bcur) * BSZ;                                \
            _Pragma("unroll")                                                    \
            for (int j = 0; j < 4; ++j) b[j] = *(const bfrag*)&B_[LDSIDX(wn + j * 16 + l15, kcc)]; \
            _Pragma("unroll")                                                    \
            for (int i = 0; i < 4; ++i) a[i] = *(const bfrag*)&A_[LDSIDX(wm + i * 16 + l15, kcc)]; \
            __builtin_amdgcn_s_setprio(1);                                       \
            _Pragma("unroll")                                                    \
            for (int i = 0; i < 4; ++i)                                          \
                _Pragma("unroll")                                                \
                for (int j = 0; j < 4; ++j)                                      \
                    acc[i][j] = __builtin_amdgcn_mfma_f32_16x16x32_bf16(a[i], b[j], acc[i][j], 0, 0, 0); \
            __builtin_amdgcn_s_setprio(0);                                       \
        } while (0)

        STG1(0, 0); STG1(1, 1); STG1(2, 2); STG1(3, 3);
        int bc = 0, bs = 4;
#pragma unroll 1
        for (int X = 0; X <= NSUB1 - 4; ++X) {
            WAITVM(9);
            BARRIER();
            STG1(bs, X + 4);
            COMP1(bc);
            bc = (bc == NBUF - 1) ? 0 : bc + 1;
            bs = (bs == NBUF - 1) ? 0 : bs + 1;
        }
        WAITVM(6); BARRIER(); COMP1(bc); bc = (bc == NBUF - 1) ? 0 : bc + 1;
        WAITVM(3); BARRIER(); COMP1(bc); bc = (bc == NBUF - 1) ? 0 : bc + 1;
        WAITVM(0); BARRIER(); COMP1(bc);
#undef COMP1
#undef STG1

        // epilogue: frag pairs (j, j+1) = (h1, h3) for same 16 hidden cols
#pragma unroll
        for (int i = 0; i < 4; ++i) {
            int rbase = wm + i * 16 + ((lane >> 4) << 2);
#pragma unroll
            for (int q = 0; q < 4; ++q) {
                int rl = rbase + q;
                if (rl >= nrows) continue;
                size_t rowoff = (size_t)(m0 + rl) * HID;
#pragma unroll
                for (int jf = 0; jf < 4; jf += 2) {
                    int gg = (wn >> 4) + jf;
                    int col = nt * 128 + ((gg >> 1) << 4) + l15;
                    float h1 = acc[i][jf][q], h3 = acc[i][jf + 1][q];
                    H[rowoff + col] = f2bf((h1 / (1.f + __expf(-h1))) * h3);
                }
            }
        }
    }
}

// ---------------- GEMM B: out[tok,:] += pw[pos] * (H[pos,:] @ w2^T) ----------------
// item = (desc d, nt 0..3): 128 H-rows x 256 out cols. items = ndesc * 4.
__global__ __launch_bounds__(512, 2) void k_ffn2(const ushort* __restrict__ H,
                                                 const ushort* __restrict__ w2b,
                                                 const int* __restrict__ offs,
                                                 const int* __restrict__ perm,
                                                 const float* __restrict__ pw,
                                                 const int* __restrict__ desc,
                                                 const int* __restrict__ ndesc_g,
                                                 float* __restrict__ out) {
    __shared__ ushort lA[NBUF * ASZ];
    __shared__ ushort lB[NBUF * BSZ];
    __shared__ int lTok[128];
    __shared__ float lPw[128];

    const int tid = threadIdx.x;
    const int lane = tid & 63, wid = tid >> 6;
    const int l15 = lane & 15, kcc = lane >> 4;
    const int wm = (wid >> 2) * 64;
    const int wn = (wid & 3) * 64;

    const int nitems = ndesc_g[0] << 2;

    const int rA = SLOT_R(tid), kcA = SLOT_KC(tid);

    bfrag a[4], b[4];
    ffrag acc[4][4];

#pragma unroll 1
    for (int w = blockIdx.x; w < nitems; w += (int)gridDim.x) {
        __syncthreads();
        const int de = desc[w >> 2];
        const int e = de >> 16, mt = de & 0xffff, nt = w & 3;
        const int m0 = offs[e] + (mt << 7);
        const int nrows = min(128, offs[e + 1] - m0);
        if (tid < 128) {
            bool v = tid < nrows;
            lTok[tid] = v ? perm[m0 + tid] : 0;
            lPw[tid]  = v ? pw[m0 + tid] : 0.f;
        }
        __syncthreads();

        int posA = m0 + rA; if (posA > 2 * TK - 1) posA = 2 * TK - 1;   // clamp into H
        const ushort* pA = H + (size_t)posA * HID + kcA * 8;
        const ushort* pBp[2];
        {
            const size_t ebase = (size_t)e * DIM * HID;
#pragma unroll
            for (int i2 = 0; i2 < 2; ++i2) {
                int s = i2 * 512 + tid;
                int r = SLOT_R(s), kc = SLOT_KC(s);
                pBp[i2] = w2b + ebase + (size_t)(nt * 256 + r) * HID + kc * 8;
            }
        }

#pragma unroll
        for (int i = 0; i < 4; ++i)
#pragma unroll
            for (int j = 0; j < 4; ++j) acc[i][j] = (ffrag)0.f;

#define STG2(buf, sx) do { if ((sx) < NSUB2) {                                   \
            gld16(pA + (sx) * SK, lA + (buf) * ASZ + (wid * 64) * 8);            \
            gld16(pBp[0] + (sx) * SK, lB + (buf) * BSZ + (wid * 64) * 8);        \
            gld16(pBp[1] + (sx) * SK, lB + (buf) * BSZ + (512 + wid * 64) * 8); } } while (0)

#define COMP2(bcur) do {                                                         \
            const ushort* A_ = lA + (bcur) * ASZ;                                \
            const ushort* B_ = lB + (bcur) * BSZ;                                \
            _Pragma("unroll")                                                    \
            for (int j = 0; j < 4; ++j) b[j] = *(const bfrag*)&B_[LDSIDX(wn + j * 16 + l15, kcc)]; \
            _Pragma("unroll")                                                    \
            for (int i = 0; i < 4; ++i) a[i] = *(const bfrag*)&A_[LDSIDX(wm + i * 16 + l15, kcc)]; \
            __builtin_amdgcn_s_setprio(1);                                       \
            _Pragma("unroll")                                                    \
            for (int i = 0; i < 4; ++i)                                          \
                _Pragma("unroll")                                                \
                for (int j = 0; j < 4; ++j)                                      \
                    acc[i][j] = __builtin_amdgcn_mfma_f32_16x16x32_bf16(a[i], b[j], acc[i][j], 0, 0, 0); \
            __builtin_amdgcn_s_setprio(0);                                       \
        } while (0)

        STG2(0, 0); STG2(1, 1); STG2(2, 2); STG2(3, 3);
        int bc = 0, bs = 4;
#pragma unroll 1
        for (int X = 0; X <= NSUB2 - 4; ++X) {
            WAITVM(9);
            BARRIER();
            STG2(bs, X + 4);
            COMP2(bc);
            bc = (bc == NBUF - 1) ? 0 : bc + 1;
            bs = (bs == NBUF - 1) ? 0 : bs + 1;
        }
        WAITVM(6); BARRIER(); COMP2(bc); bc = (bc == NBUF - 1) ? 0 : bc + 1;
        WAITVM(3); BARRIER(); COMP2(bc); bc = (bc == NBUF - 1) ? 0 : bc + 1;
        WAITVM(0); BARRIER(); COMP2(bc);
#undef COMP2
#undef STG2

#pragma unroll
        for (int i = 0; i < 4; ++i) {
            int rbase = wm + i * 16 + ((lane >> 4) << 2);
#pragma unroll
            for (int q = 0; q < 4; ++q) {
                int rl = rbase + q;
                if (rl >= nrows) continue;
                int tok = lTok[rl];
                float wgt = lPw[rl];
                size_t rowoff = (size_t)tok * DIM;
#pragma unroll
                for (int j = 0; j < 4; ++j) {
                    int col = nt * 256 + wn + j * 16 + l15;
                    atomicAdd(&out[rowoff + col], acc[i][j][q] * wgt);   // 2 adds/elem, deterministic
                }
            }
        }
    }
}

extern "C" void kernel_launch(void* const* d_in, const int* in_sizes, int n_in,
                              void* d_out, int out_size, void* d_ws, size_t ws_size,
                              hipStream_t stream) {
    const float* x  = (const float*)d_in[0];
    const float* gw = (const float*)d_in[1];
    const float* w1 = (const float*)d_in[2];
    const float* w2 = (const float*)d_in[3];   // dict order: x, gate_w, w1, w2, w3 !
    const float* w3 = (const float*)d_in[4];
    float* out = (float*)d_out;

    char* ws = (char*)d_ws;
    int*    topi   = (int*)(ws + 0);
    float*  topw   = (float*)(ws + 65536);
    int*    perm   = (int*)(ws + 131072);
    float*  pw     = (float*)(ws + 196608);
    int*    counts = (int*)(ws + 262144);
    int*    offs   = (int*)(ws + 262144 + 256);
    int*    cursor = (int*)(ws + 262144 + 512);
    int*    ndesc  = (int*)(ws + 262144 + 768);
    int*    desc   = (int*)(ws + 262144 + 1024);   // <= ~150 entries

    const size_t OFF_XB = 524288;                       // xb: 16 MiB
    const size_t OFF_H  = OFF_XB + 16777216;            // H : 128 MiB
    const size_t OFF_WA = OFF_H + 134217728;            // w1b, later w2b: 64 MiB
    const size_t OFF_WB = OFF_WA + 67108864;            // w3b: 64 MiB

    ushort* xb  = (ushort*)(ws + OFF_XB);
    ushort* H   = (ushort*)(ws + OFF_H);
    ushort* wA  = (ushort*)(ws + OFF_WA);
    ushort* wB  = (ushort*)(ws + OFF_WB);

    hipMemsetAsync(counts, 0, 32, stream);
    hipMemsetAsync(out, 0, (size_t)out_size * sizeof(float), stream);

    k_router<<<dim3(TK / 4), 256, 0, stream>>>(x, gw, topi, topw);
    k_count<<<dim3((2 * TK) / 256), 256, 0, stream>>>(topi, counts);
    k_scan<<<dim3(1), 64, 0, stream>>>(counts, offs, cursor, desc, ndesc);
    k_scatter<<<dim3(TK / 256), 256, 0, stream>>>(topi, topw, cursor, perm, pw);

    k_cvt<<<dim3((TK * DIM / 8) / 256), 256, 0, stream>>>(x, xb, TK * DIM / 8);
    k_cvt<<<dim3((NE * HID * DIM / 8) / 256), 256, 0, stream>>>(w1, wA, NE * HID * DIM / 8);
    k_cvt<<<dim3((NE * HID * DIM / 8) / 256), 256, 0, stream>>>(w3, wB, NE * HID * DIM / 8);

    k_ffn1<<<dim3(256), 512, 0, stream>>>(xb, wA, wB, offs, perm, desc, ndesc, H);

    // w1b dead now; reuse its slot for w2b
    k_cvt<<<dim3((NE * DIM * HID / 8) / 256), 256, 0, stream>>>(w2, wA, NE * DIM * HID / 8);

    k_ffn2<<<dim3(256), 512, 0, stream>>>(H, wA, offs, perm, pw, desc, ndesc, out);
}

// Round 10
// 1092.188 us; speedup vs baseline: 1.3508x; 1.3167x over previous
//
#include <hip/hip_runtime.h>
#include <hip/hip_bf16.h>
#include <cstdint>
#include <cstddef>

#define TK 8192
#define DIM 1024
#define HID 4096
#define NE 8

#define SK 32                  // K subtile
#define NSUB1 (DIM / SK)       // 32
#define NSUB2 (HID / SK)       // 128
#define ASZ 4096               // ushorts: A buffer 128 rows x 32
#define BSZ 8192               // ushorts: B buffer 256 rows x 32

typedef __attribute__((ext_vector_type(8))) __bf16 bfrag;
typedef __attribute__((ext_vector_type(4))) float ffrag;

static __device__ __forceinline__ ushort f2bf(float f) {
    union { float f; uint32_t u; } v; v.f = f;
    uint32_t r = (v.u + 0x7fffu + ((v.u >> 16) & 1u)) >> 16;   // RNE, finite only
    return (ushort)r;
}

static __device__ __forceinline__ uint4 pack8(float4 a, float4 b) {
    union { ushort u[8]; uint4 q; } pk;
    pk.u[0] = f2bf(a.x); pk.u[1] = f2bf(a.y); pk.u[2] = f2bf(a.z); pk.u[3] = f2bf(a.w);
    pk.u[4] = f2bf(b.x); pk.u[5] = f2bf(b.y); pk.u[6] = f2bf(b.z); pk.u[7] = f2bf(b.w);
    return pk.q;
}

static __device__ __forceinline__ void gld16(const ushort* g, ushort* l) {
    __builtin_amdgcn_global_load_lds(
        (const __attribute__((address_space(1))) unsigned int*)g,
        (__attribute__((address_space(3))) unsigned int*)l, 16, 0, 0);
}

#define BARRIER() asm volatile("s_barrier" ::: "memory")
#define WAITVM(N) asm volatile("s_waitcnt vmcnt(" #N ")" ::: "memory")

// LDS subtile [R rows][32 bf16], superblocks of 8 rows x 4 chunks(16B):
// chunk (r,kc) at 16B-slot (r>>3)*32 + kc*8 + (r&7); 0 bank conflicts measured (r3-r8).
// gld16 linear slot s: r = (s>>5)*8 + (s&7), kc = (s>>3)&3.
#define LDSIDX(r, kc) ((((r) >> 3) << 8) + ((kc) << 6) + (((r) & 7) << 3))
#define SLOT_R(s)  ((((s) >> 5) << 3) | ((s) & 7))
#define SLOT_KC(s) (((s) >> 3) & 3)

// ---------------- f32 -> bf16 streaming convert ----------------
__global__ __launch_bounds__(256) void k_cvt(const float* __restrict__ src,
                                             ushort* __restrict__ dst, int n8) {
    int i = blockIdx.x * blockDim.x + threadIdx.x;
    if (i >= n8) return;
    const float4* p = (const float4*)src + (size_t)i * 2;
    ((uint4*)dst)[i] = pack8(p[0], p[1]);
}

// ---------------- router: f64-accurate logits, top-2, renormalized ----------------
__global__ __launch_bounds__(256) void k_router(const float* __restrict__ x,
                                                const float* __restrict__ gw,
                                                int* __restrict__ topi, float* __restrict__ topw) {
    int t = blockIdx.x * 4 + (threadIdx.x >> 6);
    int lane = threadIdx.x & 63;
    if (t >= TK) return;
    double acc[NE];
#pragma unroll
    for (int e = 0; e < NE; ++e) acc[e] = 0.0;
    const float* xr = x + (size_t)t * DIM;
    for (int k = lane; k < DIM; k += 64) {
        double xv = (double)xr[k];
#pragma unroll
        for (int e = 0; e < NE; ++e) acc[e] += xv * (double)gw[e * DIM + k];
    }
#pragma unroll
    for (int e = 0; e < NE; ++e) {
#pragma unroll
        for (int off = 32; off > 0; off >>= 1) acc[e] += __shfl_xor(acc[e], off);
    }
    if (lane == 0) {
        int i1 = 0;
#pragma unroll
        for (int e = 1; e < NE; ++e) if (acc[e] > acc[i1]) i1 = e;
        int i2 = (i1 == 0) ? 1 : 0;
#pragma unroll
        for (int e = 0; e < NE; ++e) if (e != i1 && acc[e] > acc[i2]) i2 = e;
        double w = 1.0 / (1.0 + exp(acc[i2] - acc[i1]));
        topi[t * 2 + 0] = i1; topi[t * 2 + 1] = i2;
        topw[t * 2 + 0] = (float)w; topw[t * 2 + 1] = (float)(1.0 - w);
    }
}

__global__ void k_count(const int* __restrict__ topi, int* __restrict__ counts) {
    int i = blockIdx.x * blockDim.x + threadIdx.x;
    if (i < 2 * TK) atomicAdd(&counts[topi[i]], 1);
}

// builds per-expert offsets AND the M=128 tile descriptor list
__global__ void k_scan(const int* __restrict__ counts, int* __restrict__ offs,
                       int* __restrict__ cursor, int* __restrict__ desc,
                       int* __restrict__ ndesc) {
    if (threadIdx.x == 0 && blockIdx.x == 0) {
        int s = 0, d = 0;
        for (int e = 0; e < NE; ++e) {
            offs[e] = s; cursor[e] = s;
            int tiles = (counts[e] + 127) >> 7;
            for (int t = 0; t < tiles; ++t) desc[d++] = (e << 16) | t;
            s += counts[e];
        }
        offs[NE] = s;
        ndesc[0] = d;
    }
}

__global__ void k_scatter(const int* __restrict__ topi, const float* __restrict__ topw,
                          int* __restrict__ cursor, int* __restrict__ perm, float* __restrict__ pw) {
    int t = blockIdx.x * blockDim.x + threadIdx.x;
    if (t >= TK) return;
#pragma unroll
    for (int k = 0; k < 2; ++k) {
        int e = topi[t * 2 + k];
        int pos = atomicAdd(&cursor[e], 1);
        perm[pos] = t; pw[pos] = topw[t * 2 + k];
    }
}

// ================= persistent GEMM cores =================
// Block: 128(M) x 256(B-rows), 256 threads = 4 waves, per-wave 128x64 (m201
// geometry): 32 MFMA + 12 ds_read_b128 per K=32 subtile per wave.
// NBUF=3; ledger: 6 gld16/thread/subtile, prologue stages 0,1 (12 in flight);
// iter X: WAITVM(6) retires X exactly; stage X+2 after barrier (buffer (X+2)%3
// was fully read at iter X-1 -> safe after barrier X). Last iter WAITVM(0).

// ---------------- GEMM A (fused): H = silu(x@w1^T) * (x@w3^T) ----------------
// B rows interleave w1/w3 in 16-row groups -> (h1,h3) pairs wave-local; item
// covers 128 tokens x 128 hidden cols. items = ndesc * 32.
__global__ __launch_bounds__(256, 2) void k_ffn1(const ushort* __restrict__ xb,
                                                 const ushort* __restrict__ w1b,
                                                 const ushort* __restrict__ w3b,
                                                 const int* __restrict__ offs,
                                                 const int* __restrict__ perm,
                                                 const int* __restrict__ desc,
                                                 const int* __restrict__ ndesc_g,
                                                 ushort* __restrict__ H) {
    __shared__ ushort lA[3 * ASZ];   // 24 KiB
    __shared__ ushort lB[3 * BSZ];   // 48 KiB
    __shared__ int lTok[128];

    const int tid = threadIdx.x;
    const int lane = tid & 63, wid = tid >> 6;      // 4 waves
    const int l15 = lane & 15, kcc = lane >> 4;
    const int wn = wid * 64;                        // N-strip per wave
    const int gbase = wn >> 4;

    const int nitems = ndesc_g[0] << 5;

    const int rA0 = SLOT_R(tid), kA0 = SLOT_KC(tid);
    const int rA1 = SLOT_R(tid + 256), kA1 = SLOT_KC(tid + 256);

    bfrag a[4], b[4];
    ffrag acc[8][4];

#pragma unroll 1
    for (int w = blockIdx.x; w < nitems; w += (int)gridDim.x) {
        __syncthreads();   // prev item fully done with LDS
        const int de = desc[w >> 5];
        const int e = de >> 16, mt = de & 0xffff, nt = w & 31;
        const int m0 = offs[e] + (mt << 7);
        const int nrows = min(128, offs[e + 1] - m0);
        if (tid < 128) lTok[tid] = (tid < nrows) ? perm[m0 + tid] : perm[m0];  // pad -> valid row, discarded
        __syncthreads();

        const ushort* pA0 = xb + (size_t)lTok[rA0] * DIM + kA0 * 8;
        const ushort* pA1 = xb + (size_t)lTok[rA1] * DIM + kA1 * 8;
        const ushort* pB[4];
        {
            const size_t ebase = (size_t)e * HID * DIM;
#pragma unroll
            for (int c = 0; c < 4; ++c) {
                int s = c * 256 + tid;
                int r = SLOT_R(s), kc = SLOT_KC(s);
                int gg = r >> 4;
                int h = ((gg >> 1) << 4) | (r & 15);
                const ushort* wsrc = (gg & 1) ? w3b : w1b;
                pB[c] = wsrc + ebase + (size_t)(nt * 128 + h) * DIM + kc * 8;
            }
        }

#pragma unroll
        for (int i = 0; i < 8; ++i)
#pragma unroll
            for (int j = 0; j < 4; ++j) acc[i][j] = (ffrag)0.f;

#define STG1(buf, sx) do { if ((sx) < NSUB1) {                                    \
            gld16(pA0 + (sx) * SK, lA + (buf) * ASZ + (wid * 64) * 8);            \
            gld16(pA1 + (sx) * SK, lA + (buf) * ASZ + (256 + wid * 64) * 8);      \
            gld16(pB[0] + (sx) * SK, lB + (buf) * BSZ + (wid * 64) * 8);          \
            gld16(pB[1] + (sx) * SK, lB + (buf) * BSZ + (256 + wid * 64) * 8);    \
            gld16(pB[2] + (sx) * SK, lB + (buf) * BSZ + (512 + wid * 64) * 8);    \
            gld16(pB[3] + (sx) * SK, lB + (buf) * BSZ + (768 + wid * 64) * 8); } } while (0)

        STG1(0, 0); STG1(1, 1);
        int bc = 0, bs = 2;
#pragma unroll 1
        for (int X = 0; X < NSUB1; ++X) {
            if (X < NSUB1 - 1) { WAITVM(6); } else { WAITVM(0); }
            BARRIER();
            const ushort* A_ = lA + bc * ASZ;
            const ushort* B_ = lB + bc * BSZ;
#pragma unroll
            for (int j = 0; j < 4; ++j) b[j] = *(const bfrag*)&B_[LDSIDX(wn + j * 16 + l15, kcc)];
#pragma unroll
            for (int i = 0; i < 4; ++i) a[i] = *(const bfrag*)&A_[LDSIDX(i * 16 + l15, kcc)];
            STG1(bs, X + 2);
            __builtin_amdgcn_s_setprio(1);
#pragma unroll
            for (int i = 0; i < 4; ++i)
#pragma unroll
                for (int j = 0; j < 4; ++j)
                    acc[i][j] = __builtin_amdgcn_mfma_f32_16x16x32_bf16(a[i], b[j], acc[i][j], 0, 0, 0);
            __builtin_amdgcn_s_setprio(0);
#pragma unroll
            for (int i = 0; i < 4; ++i) a[i] = *(const bfrag*)&A_[LDSIDX(64 + i * 16 + l15, kcc)];
            __builtin_amdgcn_s_setprio(1);
#pragma unroll
            for (int i = 0; i < 4; ++i)
#pragma unroll
                for (int j = 0; j < 4; ++j)
                    acc[4 + i][j] = __builtin_amdgcn_mfma_f32_16x16x32_bf16(a[i], b[j], acc[4 + i][j], 0, 0, 0);
            __builtin_amdgcn_s_setprio(0);
            bc = (bc == 2) ? 0 : bc + 1;
            bs = (bs == 2) ? 0 : bs + 1;
        }
#undef STG1

        // epilogue: frag pairs (jf, jf+1) = (h1, h3) for same 16 hidden cols
#pragma unroll
        for (int i = 0; i < 8; ++i) {
            int rbase = i * 16 + ((lane >> 4) << 2);
#pragma unroll
            for (int q = 0; q < 4; ++q) {
                int rl = rbase + q;
                if (rl >= nrows) continue;
                size_t rowoff = (size_t)(m0 + rl) * HID;
#pragma unroll
                for (int jf = 0; jf < 4; jf += 2) {
                    int gg = gbase + jf;
                    int col = nt * 128 + ((gg >> 1) << 4) + l15;
                    float h1 = acc[i][jf][q], h3 = acc[i][jf + 1][q];
                    H[rowoff + col] = f2bf((h1 / (1.f + __expf(-h1))) * h3);
                }
            }
        }
    }
}

// ---------------- GEMM B: out[tok,:] += pw[pos] * (H[pos,:] @ w2^T) ----------------
// item = (desc d, nt 0..3): 128 H-rows x 256 out cols. items = ndesc * 4.
__global__ __launch_bounds__(256, 2) void k_ffn2(const ushort* __restrict__ H,
                                                 const ushort* __restrict__ w2b,
                                                 const int* __restrict__ offs,
                                                 const int* __restrict__ perm,
                                                 const float* __restrict__ pw,
                                                 const int* __restrict__ desc,
                                                 const int* __restrict__ ndesc_g,
                                                 float* __restrict__ out) {
    __shared__ ushort lA[3 * ASZ];
    __shared__ ushort lB[3 * BSZ];
    __shared__ int lTok[128];
    __shared__ float lPw[128];

    const int tid = threadIdx.x;
    const int lane = tid & 63, wid = tid >> 6;
    const int l15 = lane & 15, kcc = lane >> 4;
    const int wn = wid * 64;

    const int nitems = ndesc_g[0] << 2;

    const int rA0 = SLOT_R(tid), kA0 = SLOT_KC(tid);
    const int rA1 = SLOT_R(tid + 256), kA1 = SLOT_KC(tid + 256);

    bfrag a[4], b[4];
    ffrag acc[8][4];

#pragma unroll 1
    for (int w = blockIdx.x; w < nitems; w += (int)gridDim.x) {
        __syncthreads();
        const int de = desc[w >> 2];
        const int e = de >> 16, mt = de & 0xffff, nt = w & 3;
        const int m0 = offs[e] + (mt << 7);
        const int nrows = min(128, offs[e + 1] - m0);
        if (tid < 128) {
            bool v = tid < nrows;
            lTok[tid] = v ? perm[m0 + tid] : 0;
            lPw[tid]  = v ? pw[m0 + tid] : 0.f;
        }
        __syncthreads();

        int p0 = m0 + rA0; if (p0 > 2 * TK - 1) p0 = 2 * TK - 1;   // clamp into H
        int p1 = m0 + rA1; if (p1 > 2 * TK - 1) p1 = 2 * TK - 1;
        const ushort* pA0 = H + (size_t)p0 * HID + kA0 * 8;
        const ushort* pA1 = H + (size_t)p1 * HID + kA1 * 8;
        const ushort* pB[4];
        {
            const size_t ebase = (size_t)e * DIM * HID;
#pragma unroll
            for (int c = 0; c < 4; ++c) {
                int s = c * 256 + tid;
                int r = SLOT_R(s), kc = SLOT_KC(s);
                pB[c] = w2b + ebase + (size_t)(nt * 256 + r) * HID + kc * 8;
            }
        }

#pragma unroll
        for (int i = 0; i < 8; ++i)
#pragma unroll
            for (int j = 0; j < 4; ++j) acc[i][j] = (ffrag)0.f;

#define STG2(buf, sx) do { if ((sx) < NSUB2) {                                    \
            gld16(pA0 + (sx) * SK, lA + (buf) * ASZ + (wid * 64) * 8);            \
            gld16(pA1 + (sx) * SK, lA + (buf) * ASZ + (256 + wid * 64) * 8);      \
            gld16(pB[0] + (sx) * SK, lB + (buf) * BSZ + (wid * 64) * 8);          \
            gld16(pB[1] + (sx) * SK, lB + (buf) * BSZ + (256 + wid * 64) * 8);    \
            gld16(pB[2] + (sx) * SK, lB + (buf) * BSZ + (512 + wid * 64) * 8);    \
            gld16(pB[3] + (sx) * SK, lB + (buf) * BSZ + (768 + wid * 64) * 8); } } while (0)

        STG2(0, 0); STG2(1, 1);
        int bc = 0, bs = 2;
#pragma unroll 1
        for (int X = 0; X < NSUB2; ++X) {
            if (X < NSUB2 - 1) { WAITVM(6); } else { WAITVM(0); }
            BARRIER();
            const ushort* A_ = lA + bc * ASZ;
            const ushort* B_ = lB + bc * BSZ;
#pragma unroll
            for (int j = 0; j < 4; ++j) b[j] = *(const bfrag*)&B_[LDSIDX(wn + j * 16 + l15, kcc)];
#pragma unroll
            for (int i = 0; i < 4; ++i) a[i] = *(const bfrag*)&A_[LDSIDX(i * 16 + l15, kcc)];
            STG2(bs, X + 2);
            __builtin_amdgcn_s_setprio(1);
#pragma unroll
            for (int i = 0; i < 4; ++i)
#pragma unroll
                for (int j = 0; j < 4; ++j)
                    acc[i][j] = __builtin_amdgcn_mfma_f32_16x16x32_bf16(a[i], b[j], acc[i][j], 0, 0, 0);
            __builtin_amdgcn_s_setprio(0);
#pragma unroll
            for (int i = 0; i < 4; ++i) a[i] = *(const bfrag*)&A_[LDSIDX(64 + i * 16 + l15, kcc)];
            __builtin_amdgcn_s_setprio(1);
#pragma unroll
            for (int i = 0; i < 4; ++i)
#pragma unroll
                for (int j = 0; j < 4; ++j)
                    acc[4 + i][j] = __builtin_amdgcn_mfma_f32_16x16x32_bf16(a[i], b[j], acc[4 + i][j], 0, 0, 0);
            __builtin_amdgcn_s_setprio(0);
            bc = (bc == 2) ? 0 : bc + 1;
            bs = (bs == 2) ? 0 : bs + 1;
        }
#undef STG2

#pragma unroll
        for (int i = 0; i < 8; ++i) {
            int rbase = i * 16 + ((lane >> 4) << 2);
#pragma unroll
            for (int q = 0; q < 4; ++q) {
                int rl = rbase + q;
                if (rl >= nrows) continue;
                int tok = lTok[rl];
                float wgt = lPw[rl];
                size_t rowoff = (size_t)tok * DIM;
#pragma unroll
                for (int j = 0; j < 4; ++j) {
                    int col = nt * 256 + wn + j * 16 + l15;
                    atomicAdd(&out[rowoff + col], acc[i][j][q] * wgt);   // 2 adds/elem, deterministic
                }
            }
        }
    }
}

extern "C" void kernel_launch(void* const* d_in, const int* in_sizes, int n_in,
                              void* d_out, int out_size, void* d_ws, size_t ws_size,
                              hipStream_t stream) {
    const float* x  = (const float*)d_in[0];
    const float* gw = (const float*)d_in[1];
    const float* w1 = (const float*)d_in[2];
    const float* w2 = (const float*)d_in[3];   // dict order: x, gate_w, w1, w2, w3 !
    const float* w3 = (const float*)d_in[4];
    float* out = (float*)d_out;

    char* ws = (char*)d_ws;
    int*    topi   = (int*)(ws + 0);
    float*  topw   = (float*)(ws + 65536);
    int*    perm   = (int*)(ws + 131072);
    float*  pw     = (float*)(ws + 196608);
    int*    counts = (int*)(ws + 262144);
    int*    offs   = (int*)(ws + 262144 + 256);
    int*    cursor = (int*)(ws + 262144 + 512);
    int*    ndesc  = (int*)(ws + 262144 + 768);
    int*    desc   = (int*)(ws + 262144 + 1024);

    const size_t OFF_XB = 524288;                       // xb: 16 MiB
    const size_t OFF_H  = OFF_XB + 16777216;            // H : 128 MiB
    const size_t OFF_WA = OFF_H + 134217728;            // w1b, later w2b: 64 MiB
    const size_t OFF_WB = OFF_WA + 67108864;            // w3b: 64 MiB

    ushort* xb  = (ushort*)(ws + OFF_XB);
    ushort* H   = (ushort*)(ws + OFF_H);
    ushort* wA  = (ushort*)(ws + OFF_WA);
    ushort* wB  = (ushort*)(ws + OFF_WB);

    hipMemsetAsync(counts, 0, 32, stream);
    hipMemsetAsync(out, 0, (size_t)out_size * sizeof(float), stream);

    k_router<<<dim3(TK / 4), 256, 0, stream>>>(x, gw, topi, topw);
    k_count<<<dim3((2 * TK) / 256), 256, 0, stream>>>(topi, counts);
    k_scan<<<dim3(1), 64, 0, stream>>>(counts, offs, cursor, desc, ndesc);
    k_scatter<<<dim3(TK / 256), 256, 0, stream>>>(topi, topw, cursor, perm, pw);

    k_cvt<<<dim3((TK * DIM / 8) / 256), 256, 0, stream>>>(x, xb, TK * DIM / 8);
    k_cvt<<<dim3((NE * HID * DIM / 8) / 256), 256, 0, stream>>>(w1, wA, NE * HID * DIM / 8);
    k_cvt<<<dim3((NE * HID * DIM / 8) / 256), 256, 0, stream>>>(w3, wB, NE * HID * DIM / 8);

    k_ffn1<<<dim3(512), 256, 0, stream>>>(xb, wA, wB, offs, perm, desc, ndesc, H);

    // w1b dead now; reuse its slot for w2b
    k_cvt<<<dim3((NE * DIM * HID / 8) / 256), 256, 0, stream>>>(w2, wA, NE * DIM * HID / 8);

    k_ffn2<<<dim3(512), 256, 0, stream>>>(H, wA, offs, perm, pw, desc, ndesc, out);
}